// Round 5
// baseline (228.715 us; speedup 1.0000x reference)
//
#include <hip/hip_runtime.h>

// TT Q-gather, ALL cores through LDS (no precomputed tables, d_ws unused).
//   v = G0[0, s0, :]          (G0 staged+swizzled in LDS, round 0)
//   for k=1..6: v = v @ Gk[:, sk, :]   (64KB core staged in LDS, XOR swizzle)
//   q = v . G7[:, a7, 0]      (G7 staged linear in LDS, b32 column gather)
//
// Round-4 lesson: random 32B gathers into 4MB global tables generated
// ~190MB of TCC traffic (L2 thrash vs streaming states + dirty ws-poison
// evictions). All-LDS removes every divergent global access.
//
// LDS (64KB, reused): matrix n at float4 slots [n*16..n*16+15]; chunk
// c=2r+h stored at slot c^(n&15) -> random-n gather spreads all 8 bank
// phases (measured +2cy/instr over floor). G0 row n chunks (2n+h) stored
// at (2n+h)^(n&15): conflict-free write and near-uniform gather.

#define NN 256
#define RR 8
#define NR 2048   // N * R

// stage 64KB core G into swizzled LDS; fused load->store
#define STAGE(Gp)                                                           \
    do {                                                                    \
        __syncthreads();                                                    \
        _Pragma("unroll") for (int i = 0; i < 4; ++i) {                     \
            int pidx = t + (i << 9);                                        \
            int r = pidx >> 8;                                              \
            int n = pidx & 255;                                             \
            const float4* gp = (const float4*)((Gp) + r * NR + n * RR);     \
            float4 x = gp[0];                                               \
            float4 y = gp[1];                                               \
            int xm = n & 15;                                                \
            lds[(n << 4) + ((2 * r) ^ xm)]     = x;                         \
            lds[(n << 4) + ((2 * r + 1) ^ xm)] = y;                         \
        }                                                                   \
        __syncthreads();                                                    \
    } while (0)

// gather matrix nidx from LDS and do v = v @ M
#define GATHER(nidx)                                                        \
    do {                                                                    \
        const float4* mp = lds + ((nidx) << 4);                             \
        int xm = (nidx) & 15;                                               \
        float nv0 = 0.f, nv1 = 0.f, nv2 = 0.f, nv3 = 0.f;                   \
        float nv4 = 0.f, nv5 = 0.f, nv6 = 0.f, nv7 = 0.f;                   \
        _Pragma("unroll") for (int r = 0; r < 8; ++r) {                     \
            float4 x = mp[(2 * r) ^ xm];                                    \
            float4 y = mp[(2 * r + 1) ^ xm];                                \
            float vr = v[r];                                                \
            nv0 += vr * x.x; nv1 += vr * x.y;                               \
            nv2 += vr * x.z; nv3 += vr * x.w;                               \
            nv4 += vr * y.x; nv5 += vr * y.y;                               \
            nv6 += vr * y.z; nv7 += vr * y.w;                               \
        }                                                                   \
        v[0] = nv0; v[1] = nv1; v[2] = nv2; v[3] = nv3;                     \
        v[4] = nv4; v[5] = nv5; v[6] = nv6; v[7] = nv7;                     \
    } while (0)

#define G0_BASE 896   // float4 index of G0 region (after 14336B of states)

__global__ __launch_bounds__(512, 4) void tt_all(
    const float* __restrict__ G0, const float* __restrict__ G1,
    const float* __restrict__ G2, const float* __restrict__ G3,
    const float* __restrict__ G4, const float* __restrict__ G5,
    const float* __restrict__ G6, const float* __restrict__ G7,
    const int* __restrict__ states, const int* __restrict__ actions,
    float* __restrict__ out, int B) {
    __shared__ float4 lds[NN * 16];   // 64 KB -> 2 blocks/CU

    const int t = threadIdx.x;
    const int b = blockIdx.x * 512 + t;
    const bool active = (b < B);
    const int bc = active ? b : 0;

    // ---- round 0: co-stage states rows (14336B) + G0 (8KB, swizzled) ----
    {
        int* ibuf = (int*)lds;
        const int* gsrc = states + (size_t)blockIdx.x * 512 * 7;
        const int lim = B * 7 - blockIdx.x * 512 * 7;
#pragma unroll
        for (int k = 0; k < 7; ++k) {
            int j = t + k * 512;
            if (j < lim) ibuf[j] = gsrc[j];
        }
        // G0: 512 float4 chunks; chunk t=(2n+h) -> slot t ^ ((t>>1)&15)
        const float4* g0p = (const float4*)G0;
        lds[G0_BASE + (t ^ ((t >> 1) & 15))] = g0p[t];
    }
    __syncthreads();

    const int* myrow = ((const int*)lds) + t * 7;   // stride 7: conflict-free
    const int s0 = myrow[0];
    const int s1 = myrow[1];
    const int s2 = myrow[2];
    const int s3 = myrow[3];
    const int s4 = myrow[4];
    const int s5 = myrow[5];
    const int s6 = myrow[6];
    const int a7 = actions[bc];

    float v[8];
    {
        int xm = s0 & 15;
        float4 x = lds[G0_BASE + ((2 * s0) ^ xm)];
        float4 y = lds[G0_BASE + ((2 * s0 + 1) ^ xm)];
        v[0] = x.x; v[1] = x.y; v[2] = x.z; v[3] = x.w;
        v[4] = y.x; v[5] = y.y; v[6] = y.z; v[7] = y.w;
    }

    STAGE(G1);
    GATHER(s1);
    STAGE(G2);
    GATHER(s2);
    STAGE(G3);
    GATHER(s3);
    STAGE(G4);
    GATHER(s4);
    STAGE(G5);
    GATHER(s5);
    STAGE(G6);
    GATHER(s6);

    // ---- final: stage G7 (8KB linear), dot with column a7 ----
    __syncthreads();                       // protect GATHER(s6) reads
    lds[t] = ((const float4*)G7)[t];       // 512 float4 = 8KB
    __syncthreads();

    const float* g7f = (const float*)lds;  // g7f[r*256 + n]
    float q = 0.f;
#pragma unroll
    for (int r = 0; r < 8; ++r) q += v[r] * g7f[r * NN + a7];

    if (active) out[b] = q;
}

extern "C" void kernel_launch(void* const* d_in, const int* in_sizes, int n_in,
                              void* d_out, int out_size, void* d_ws, size_t ws_size,
                              hipStream_t stream) {
    const float* G0 = (const float*)d_in[0];
    const float* G1 = (const float*)d_in[1];
    const float* G2 = (const float*)d_in[2];
    const float* G3 = (const float*)d_in[3];
    const float* G4 = (const float*)d_in[4];
    const float* G5 = (const float*)d_in[5];
    const float* G6 = (const float*)d_in[6];
    const float* G7 = (const float*)d_in[7];
    const int* states  = (const int*)d_in[8];
    const int* actions = (const int*)d_in[9];
    float* out = (float*)d_out;
    int B = in_sizes[9];

    int nblocks = (B + 511) / 512;
    hipLaunchKernelGGL(tt_all, dim3(nblocks), dim3(512), 0, stream,
                       G0, G1, G2, G3, G4, G5, G6, G7,
                       states, actions, out, B);
}

// Round 6
// 145.102 us; speedup vs baseline: 1.5762x; 1.5762x over previous
//
#include <hip/hip_runtime.h>

// TT Q-gather. Structure (R6):
//   vec = V01[s0][s1][:]                (G0*G1 fold, 2MB table in ws)
//   for k in 2..5: vec = vec @ Gk[:,sk,:]   (Gk staged in LDS, XOR swizzle)
//   q   = vec . U67[s6][a7][:]          (G6*G7 fold, 2MB table in ws)
// 2 elements/thread -> 256 blocks (halves staging storm vs R4's 512).
// build_tables warm-reads G2..G5 with 8x overlapping slices so core lines
// are cache-valid before tt_main's synchronized staging (R5 lesson: cold
// lockstep staging spawns worst-case HBM fills + dirty-poison evictions).

#define NN 256
#define RR 8
#define NR 2048   // N * R

__global__ __launch_bounds__(256) void build_tables(
    const float* __restrict__ G0, const float* __restrict__ G1,
    const float* __restrict__ G2, const float* __restrict__ G3,
    const float* __restrict__ G4, const float* __restrict__ G5,
    const float* __restrict__ G6, const float* __restrict__ G7,
    float* __restrict__ V01, float* __restrict__ U67) {
    const int t = threadIdx.x;

    // ---- warm: G2..G5 = 4 x 4096 float4 = 256KB. Block bi reads 256
    // consecutive float4 starting at bi*32 (mod 16384): 8x line overlap ->
    // consecutive blocks (round-robin over XCDs) cover every line in every
    // XCD's L2. Folded into output as +0.0f*wsum (finite, exact no-op).
    float wsum;
    {
        int off4 = ((blockIdx.x << 5) + t) & 16383;
        int core = off4 >> 12;
        int idx  = off4 & 4095;
        const float4* src = (core == 0) ? (const float4*)G2
                          : (core == 1) ? (const float4*)G3
                          : (core == 2) ? (const float4*)G4
                                        : (const float4*)G5;
        float4 w = src[idx];
        wsum = w.x + w.y + w.z + w.w;
    }

    if (blockIdx.x < NN) {
        // V01[n0][n1][s] = sum_r G0[n0,r] * G1[r,n1,s]
        const int n0 = blockIdx.x, n1 = t;
        float acc[RR] = {0.f,0.f,0.f,0.f,0.f,0.f,0.f,0.f};
#pragma unroll
        for (int r = 0; r < RR; ++r) {
            float ar = G0[n0 * RR + r];
            const float4* p = (const float4*)(G1 + r * NR + n1 * RR);
            float4 x = p[0], y = p[1];
            acc[0] += ar * x.x; acc[1] += ar * x.y;
            acc[2] += ar * x.z; acc[3] += ar * x.w;
            acc[4] += ar * y.x; acc[5] += ar * y.y;
            acc[6] += ar * y.z; acc[7] += ar * y.w;
        }
        float4* o = (float4*)(V01 + n0 * NR + n1 * RR);
        o[0] = make_float4(acc[0] + 0.0f * wsum, acc[1], acc[2], acc[3]);
        o[1] = make_float4(acc[4], acc[5], acc[6], acc[7]);
    } else {
        // U67[n6][n7][r] = sum_s G6[r,n6,s] * G7[s,n7]
        const int n6 = blockIdx.x - NN, n7 = t;
        float g7v[RR];
#pragma unroll
        for (int s = 0; s < RR; ++s) g7v[s] = G7[s * NN + n7];
        float u[RR];
#pragma unroll
        for (int r = 0; r < RR; ++r) {
            float acc = 0.f;
#pragma unroll
            for (int s = 0; s < RR; ++s)
                acc += G6[r * NR + n6 * RR + s] * g7v[s];
            u[r] = acc;
        }
        float4* o = (float4*)(U67 + n6 * NR + n7 * RR);
        o[0] = make_float4(u[0] + 0.0f * wsum, u[1], u[2], u[3]);
        o[1] = make_float4(u[4], u[5], u[6], u[7]);
    }
}

// stage 64KB core into swizzled LDS; fused load->store (no reg double-buffer)
#define STAGE(Gp)                                                           \
    do {                                                                    \
        __syncthreads();                                                    \
        _Pragma("unroll") for (int i = 0; i < 4; ++i) {                     \
            int pidx = t + (i << 9);                                        \
            int r = pidx >> 8;                                              \
            int n = pidx & 255;                                             \
            const float4* gp = (const float4*)((Gp) + r * NR + n * RR);     \
            float4 x = gp[0];                                               \
            float4 y = gp[1];                                               \
            int xm = n & 15;                                                \
            lds[(n << 4) + ((2 * r) ^ xm)]     = x;                         \
            lds[(n << 4) + ((2 * r + 1) ^ xm)] = y;                         \
        }                                                                   \
        __syncthreads();                                                    \
    } while (0)

// gather matrix nidx from LDS, v[e] = v[e] @ M   (e is a literal constant)
#define GATHER(e, nidx)                                                     \
    do {                                                                    \
        const float4* mp = lds + ((nidx) << 4);                             \
        int xm = (nidx) & 15;                                               \
        float nv0 = 0.f, nv1 = 0.f, nv2 = 0.f, nv3 = 0.f;                   \
        float nv4 = 0.f, nv5 = 0.f, nv6 = 0.f, nv7 = 0.f;                   \
        _Pragma("unroll") for (int r = 0; r < 8; ++r) {                     \
            float4 x = mp[(2 * r) ^ xm];                                    \
            float4 y = mp[(2 * r + 1) ^ xm];                                \
            float vr = v[e][r];                                             \
            nv0 += vr * x.x; nv1 += vr * x.y;                               \
            nv2 += vr * x.z; nv3 += vr * x.w;                               \
            nv4 += vr * y.x; nv5 += vr * y.y;                               \
            nv6 += vr * y.z; nv7 += vr * y.w;                               \
        }                                                                   \
        v[e][0] = nv0; v[e][1] = nv1; v[e][2] = nv2; v[e][3] = nv3;         \
        v[e][4] = nv4; v[e][5] = nv5; v[e][6] = nv6; v[e][7] = nv7;         \
    } while (0)

__global__ __launch_bounds__(512, 2) void tt_main(
    const float* __restrict__ G2, const float* __restrict__ G3,
    const float* __restrict__ G4, const float* __restrict__ G5,
    const float* __restrict__ V01, const float* __restrict__ U67,
    const int* __restrict__ states, const int* __restrict__ actions,
    float* __restrict__ out, int B) {
    __shared__ float4 lds[NN * 16];   // 64 KB

    const int t = threadIdx.x;
    const int ebase = blockIdx.x * 1024;    // 2 elements per thread

    // ---- stage this block's 1024 state rows (28672 B, coalesced) ----
    {
        int* ibuf = (int*)lds;
        const int* gsrc = states + (size_t)ebase * 7;
        const int lim = B * 7 - ebase * 7;
#pragma unroll
        for (int k = 0; k < 14; ++k) {
            int j = t + (k << 9);
            if (j < lim) ibuf[j] = gsrc[j];
        }
    }
    __syncthreads();

    const int b0 = ebase + t;
    const int b1 = ebase + 512 + t;
    const bool act0 = (b0 < B);
    const bool act1 = (b1 < B);

    // stride-7 rows: conflict-free (7 coprime with 32); &255 bounds-safety
    const int* r0 = ((const int*)lds) + t * 7;
    const int* r1 = ((const int*)lds) + (512 + t) * 7;
    const int s0_0 = r0[0] & 255, s0_1 = r1[0] & 255;
    const int s1_0 = r0[1] & 255, s1_1 = r1[1] & 255;
    const int s2_0 = r0[2] & 255, s2_1 = r1[2] & 255;
    const int s3_0 = r0[3] & 255, s3_1 = r1[3] & 255;
    const int s4_0 = r0[4] & 255, s4_1 = r1[4] & 255;
    const int s5_0 = r0[5] & 255, s5_1 = r1[5] & 255;
    const int s6_0 = r0[6] & 255, s6_1 = r1[6] & 255;
    const int a7_0 = actions[act0 ? b0 : 0] & 255;
    const int a7_1 = actions[act1 ? b1 : 0] & 255;

    float v[2][8];
    {
        const float4* p0 = (const float4*)(V01 + s0_0 * NR + s1_0 * RR);
        float4 x = p0[0], y = p0[1];
        v[0][0] = x.x; v[0][1] = x.y; v[0][2] = x.z; v[0][3] = x.w;
        v[0][4] = y.x; v[0][5] = y.y; v[0][6] = y.z; v[0][7] = y.w;
        const float4* p1 = (const float4*)(V01 + s0_1 * NR + s1_1 * RR);
        float4 x1 = p1[0], y1 = p1[1];
        v[1][0] = x1.x; v[1][1] = x1.y; v[1][2] = x1.z; v[1][3] = x1.w;
        v[1][4] = y1.x; v[1][5] = y1.y; v[1][6] = y1.z; v[1][7] = y1.w;
    }

    STAGE(G2);
    GATHER(0, s2_0);
    GATHER(1, s2_1);
    STAGE(G3);
    GATHER(0, s3_0);
    GATHER(1, s3_1);
    STAGE(G4);
    GATHER(0, s4_0);
    GATHER(1, s4_1);
    STAGE(G5);
    GATHER(0, s5_0);
    GATHER(1, s5_1);

    // ends: q_e = v[e] . U67[s6_e][a7_e][:]
    {
        const float4* p = (const float4*)(U67 + s6_0 * NR + a7_0 * RR);
        float4 x = p[0], y = p[1];
        float q = v[0][0]*x.x + v[0][1]*x.y + v[0][2]*x.z + v[0][3]*x.w
                + v[0][4]*y.x + v[0][5]*y.y + v[0][6]*y.z + v[0][7]*y.w;
        if (act0) out[b0] = q;
    }
    {
        const float4* p = (const float4*)(U67 + s6_1 * NR + a7_1 * RR);
        float4 x = p[0], y = p[1];
        float q = v[1][0]*x.x + v[1][1]*x.y + v[1][2]*x.z + v[1][3]*x.w
                + v[1][4]*y.x + v[1][5]*y.y + v[1][6]*y.z + v[1][7]*y.w;
        if (act1) out[b1] = q;
    }
}

extern "C" void kernel_launch(void* const* d_in, const int* in_sizes, int n_in,
                              void* d_out, int out_size, void* d_ws, size_t ws_size,
                              hipStream_t stream) {
    const float* G0 = (const float*)d_in[0];
    const float* G1 = (const float*)d_in[1];
    const float* G2 = (const float*)d_in[2];
    const float* G3 = (const float*)d_in[3];
    const float* G4 = (const float*)d_in[4];
    const float* G5 = (const float*)d_in[5];
    const float* G6 = (const float*)d_in[6];
    const float* G7 = (const float*)d_in[7];
    const int* states  = (const int*)d_in[8];
    const int* actions = (const int*)d_in[9];
    float* out = (float*)d_out;
    int B = in_sizes[9];

    float* V01 = (float*)d_ws;            // 2 MB
    float* U67 = V01 + NN * NN * RR;      // 2 MB

    hipLaunchKernelGGL(build_tables, dim3(2 * NN), dim3(256), 0, stream,
                       G0, G1, G2, G3, G4, G5, G6, G7, V01, U67);

    int nblocks = (B + 1023) / 1024;
    hipLaunchKernelGGL(tt_main, dim3(nblocks), dim3(512), 0, stream,
                       G2, G3, G4, G5, V01, U67, states, actions, out, B);
}

// Round 7
// 104.036 us; speedup vs baseline: 2.1984x; 1.3947x over previous
//
#include <hip/hip_runtime.h>

// TT Q-gather — direct divergent gathers from transposed bf16 cores.
//
// R1 evidence: divergent per-element gathers keep HBM traffic tiny (6.9 MB,
// cores L2-resident; requests time-spread -> no fill storms) and are bound
// purely by TA address serialization (~70 cy per 64-divergent-lane vmem
// instr). R2-R6 evidence: any per-block LDS staging / 4MB-table scheme
// generates 85-200 MB of latency-bound TCC fill traffic -> 40-165 us.
//
// This kernel halves R1's address count:
//   - cores transposed to matrix-contiguous Gt[n][r][s] in d_ws
//   - stored as bf16 (RNE), so an 8x8 matrix = 128 B = 8 dwordx4 loads
//     (vs 16 scattered fp32 loads). Compute stays fp32.
// Per elem: 1 + 6*8 + 1 = 50 divergent instrs vs R1's ~115 -> ~23 us.
//
// ws layout (ushort units):
//   G0t @ 0                      : [n][s]    256*8   (4 KB)
//   Gt_k @ 2048 + (k-1)*16384    : [n][r][s] 256*64  (32 KB), k=1..6
//   G7t @ 2048 + 6*16384 = 100352: [n][r]    256*8   (4 KB)

#define NN 256
#define RR 8
#define NR 2048   // N * R

__device__ __forceinline__ unsigned short f2bf_rne(float f) {
    unsigned int u = __float_as_uint(f);
    u += 0x7FFFu + ((u >> 16) & 1u);   // round-to-nearest-even
    return (unsigned short)(u >> 16);
}

// 50 blocks x 256 threads: blocks 0..47 transpose G1..G6, 48 -> G0, 49 -> G7
__global__ __launch_bounds__(256) void transpose_cores(
    const float* __restrict__ G0, const float* __restrict__ G1,
    const float* __restrict__ G2, const float* __restrict__ G3,
    const float* __restrict__ G4, const float* __restrict__ G5,
    const float* __restrict__ G6, const float* __restrict__ G7,
    unsigned short* __restrict__ wsb) {
    const int t = threadIdx.x;
    const int bid = blockIdx.x;

    if (bid < 48) {
        const int k = bid >> 3;                 // 0..5 -> G1..G6
        const int chunk = bid & 7;
        const float* __restrict__ Gk =
            (k == 0) ? G1 : (k == 1) ? G2 : (k == 2) ? G3
          : (k == 3) ? G4 : (k == 4) ? G5 : G6;
        const int n = chunk * 32 + (t >> 3);
        const int r = t & 7;
        const float4* src = (const float4*)(Gk + r * NR + n * RR);
        float4 x = src[0], y = src[1];
        unsigned short* dst = wsb + 2048 + k * 16384 + n * 64 + r * 8;
        unsigned int p0 = f2bf_rne(x.x) | ((unsigned int)f2bf_rne(x.y) << 16);
        unsigned int p1 = f2bf_rne(x.z) | ((unsigned int)f2bf_rne(x.w) << 16);
        unsigned int p2 = f2bf_rne(y.x) | ((unsigned int)f2bf_rne(y.y) << 16);
        unsigned int p3 = f2bf_rne(y.z) | ((unsigned int)f2bf_rne(y.w) << 16);
        *(uint4*)dst = make_uint4(p0, p1, p2, p3);
    } else if (bid == 48) {
        // G0t[n][s] = bf16(G0[n*8+s])  (already n-major, just cast)
        const int n = t;
        const float4* src = (const float4*)(G0 + n * RR);
        float4 x = src[0], y = src[1];
        unsigned short* dst = wsb + n * 8;
        unsigned int p0 = f2bf_rne(x.x) | ((unsigned int)f2bf_rne(x.y) << 16);
        unsigned int p1 = f2bf_rne(x.z) | ((unsigned int)f2bf_rne(x.w) << 16);
        unsigned int p2 = f2bf_rne(y.x) | ((unsigned int)f2bf_rne(y.y) << 16);
        unsigned int p3 = f2bf_rne(y.z) | ((unsigned int)f2bf_rne(y.w) << 16);
        *(uint4*)dst = make_uint4(p0, p1, p2, p3);
    } else {
        // G7t[n][r] = bf16(G7[r*256+n])
        const int n = t;
        float f[8];
#pragma unroll
        for (int r = 0; r < 8; ++r) f[r] = G7[r * NN + n];
        unsigned short* dst = wsb + 100352 + n * 8;
        unsigned int p0 = f2bf_rne(f[0]) | ((unsigned int)f2bf_rne(f[1]) << 16);
        unsigned int p1 = f2bf_rne(f[2]) | ((unsigned int)f2bf_rne(f[3]) << 16);
        unsigned int p2 = f2bf_rne(f[4]) | ((unsigned int)f2bf_rne(f[5]) << 16);
        unsigned int p3 = f2bf_rne(f[6]) | ((unsigned int)f2bf_rne(f[7]) << 16);
        *(uint4*)dst = make_uint4(p0, p1, p2, p3);
    }
}

#define BF2F_LO(u) __uint_as_float((u) << 16)
#define BF2F_HI(u) __uint_as_float((u) & 0xFFFF0000u)

// one chain stage: v = v @ M, M = 8x8 bf16 matrix contiguous at mp
#define BSTAGE(koff, nidx)                                                  \
    do {                                                                    \
        const uint4* mp =                                                   \
            (const uint4*)(wsb + 2048 + (koff)*16384 + (nidx)*64);          \
        float nv0 = 0.f, nv1 = 0.f, nv2 = 0.f, nv3 = 0.f;                   \
        float nv4 = 0.f, nv5 = 0.f, nv6 = 0.f, nv7 = 0.f;                   \
        _Pragma("unroll") for (int r = 0; r < 8; ++r) {                     \
            uint4 u = mp[r];                                                \
            float vr = v[r];                                                \
            nv0 += vr * BF2F_LO(u.x); nv1 += vr * BF2F_HI(u.x);             \
            nv2 += vr * BF2F_LO(u.y); nv3 += vr * BF2F_HI(u.y);             \
            nv4 += vr * BF2F_LO(u.z); nv5 += vr * BF2F_HI(u.z);             \
            nv6 += vr * BF2F_LO(u.w); nv7 += vr * BF2F_HI(u.w);             \
        }                                                                   \
        v[0] = nv0; v[1] = nv1; v[2] = nv2; v[3] = nv3;                     \
        v[4] = nv4; v[5] = nv5; v[6] = nv6; v[7] = nv7;                     \
    } while (0)

__global__ __launch_bounds__(256) void tt_gather(
    const unsigned short* __restrict__ wsb,
    const int* __restrict__ states, const int* __restrict__ actions,
    float* __restrict__ out, int B) {
    const int b = blockIdx.x * 256 + threadIdx.x;
    if (b >= B) return;

    const int* srow = states + b * 7;
    const int s0 = srow[0] & 255;
    const int s1 = srow[1] & 255;
    const int s2 = srow[2] & 255;
    const int s3 = srow[3] & 255;
    const int s4 = srow[4] & 255;
    const int s5 = srow[5] & 255;
    const int s6 = srow[6] & 255;
    const int a7 = actions[b] & 255;

    float v[8];
    {
        uint4 u = *(const uint4*)(wsb + s0 * 8);
        v[0] = BF2F_LO(u.x); v[1] = BF2F_HI(u.x);
        v[2] = BF2F_LO(u.y); v[3] = BF2F_HI(u.y);
        v[4] = BF2F_LO(u.z); v[5] = BF2F_HI(u.z);
        v[6] = BF2F_LO(u.w); v[7] = BF2F_HI(u.w);
    }

    BSTAGE(0, s1);
    BSTAGE(1, s2);
    BSTAGE(2, s3);
    BSTAGE(3, s4);
    BSTAGE(4, s5);
    BSTAGE(5, s6);

    float q;
    {
        uint4 u = *(const uint4*)(wsb + 100352 + a7 * 8);
        q = v[0] * BF2F_LO(u.x) + v[1] * BF2F_HI(u.x)
          + v[2] * BF2F_LO(u.y) + v[3] * BF2F_HI(u.y)
          + v[4] * BF2F_LO(u.z) + v[5] * BF2F_HI(u.z)
          + v[6] * BF2F_LO(u.w) + v[7] * BF2F_HI(u.w);
    }
    out[b] = q;
}

extern "C" void kernel_launch(void* const* d_in, const int* in_sizes, int n_in,
                              void* d_out, int out_size, void* d_ws, size_t ws_size,
                              hipStream_t stream) {
    const float* G0 = (const float*)d_in[0];
    const float* G1 = (const float*)d_in[1];
    const float* G2 = (const float*)d_in[2];
    const float* G3 = (const float*)d_in[3];
    const float* G4 = (const float*)d_in[4];
    const float* G5 = (const float*)d_in[5];
    const float* G6 = (const float*)d_in[6];
    const float* G7 = (const float*)d_in[7];
    const int* states  = (const int*)d_in[8];
    const int* actions = (const int*)d_in[9];
    float* out = (float*)d_out;
    int B = in_sizes[9];

    unsigned short* wsb = (unsigned short*)d_ws;   // 200 KB used

    hipLaunchKernelGGL(transpose_cores, dim3(50), dim3(256), 0, stream,
                       G0, G1, G2, G3, G4, G5, G6, G7, wsb);

    hipLaunchKernelGGL(tt_gather, dim3((B + 255) / 256), dim3(256), 0, stream,
                       wsb, states, actions, out, B);
}

// Round 8
// 101.457 us; speedup vs baseline: 2.2543x; 1.0254x over previous
//
#include <hip/hip_runtime.h>

// TT Q-gather — direct divergent gathers, bf16 storage, end-stages folded.
//
//   v = V01[s0][s1][:]      (bf16 fold of G0*G1, 1MB table in ws)
//   for k=2..5: v = v @ Gk[:,sk,:]   (bf16 transposed matrix-contiguous)
//   q = v . U67[s6][a7][:]  (bf16 fold of G6*G7, 1MB table in ws)
//
// Model (validated R1/R7): gather kernel is TA address-serialization bound,
// ~1.1 cy per divergent lane-address per CU. R7 = 59 divergent instr/elem
// -> ~27us. This round: 34 matrix-load instrs + LDS-staged states
// -> predicted ~16us. All compute fp32; bf16 adds one RNE rounding per
// stored entry (R7 margin: absmax 1.06e-22 vs 4.51e-22 threshold).
//
// ws layout (ushort units):
//   V01  @ 0       : [n0][n1][s] 256*256*8  (1 MB)
//   U67  @ 524288  : [n6][n7][r] 256*256*8  (1 MB)
//   Gt_k @ 1048576 + k*16384 : [n][r][s] 256*64 (32 KB), k=0..3 -> G2..G5

#define NN 256
#define RR 8
#define NR 2048   // N * R
#define U67_OFF 524288
#define GT_OFF  1048576

__device__ __forceinline__ unsigned short f2bf_rne(float f) {
    unsigned int u = __float_as_uint(f);
    u += 0x7FFFu + ((u >> 16) & 1u);
    return (unsigned short)(u >> 16);
}

__device__ __forceinline__ uint4 pack8bf(const float* a) {
    return make_uint4(
        f2bf_rne(a[0]) | ((unsigned int)f2bf_rne(a[1]) << 16),
        f2bf_rne(a[2]) | ((unsigned int)f2bf_rne(a[3]) << 16),
        f2bf_rne(a[4]) | ((unsigned int)f2bf_rne(a[5]) << 16),
        f2bf_rne(a[6]) | ((unsigned int)f2bf_rne(a[7]) << 16));
}

// 544 blocks x 256 threads:
//   0..255   -> V01 row n0
//   256..511 -> U67 row n6
//   512..543 -> transpose G2..G5 (8 blocks per core)
__global__ __launch_bounds__(256) void build_tables(
    const float* __restrict__ G0, const float* __restrict__ G1,
    const float* __restrict__ G2, const float* __restrict__ G3,
    const float* __restrict__ G4, const float* __restrict__ G5,
    const float* __restrict__ G6, const float* __restrict__ G7,
    unsigned short* __restrict__ wsb) {
    const int t = threadIdx.x;
    const int bid = blockIdx.x;

    if (bid < NN) {
        // V01[n0][n1][s] = sum_r G0[n0,r] * G1[r,n1,s]
        const int n0 = bid, n1 = t;
        float acc[RR] = {0.f,0.f,0.f,0.f,0.f,0.f,0.f,0.f};
#pragma unroll
        for (int r = 0; r < RR; ++r) {
            float ar = G0[n0 * RR + r];
            const float4* p = (const float4*)(G1 + r * NR + n1 * RR);
            float4 x = p[0], y = p[1];
            acc[0] += ar * x.x; acc[1] += ar * x.y;
            acc[2] += ar * x.z; acc[3] += ar * x.w;
            acc[4] += ar * y.x; acc[5] += ar * y.y;
            acc[6] += ar * y.z; acc[7] += ar * y.w;
        }
        *(uint4*)(wsb + n0 * 2048 + n1 * 8) = pack8bf(acc);
    } else if (bid < 2 * NN) {
        // U67[n6][n7][r] = sum_s G6[r,n6,s] * G7[s,n7]
        const int n6 = bid - NN, n7 = t;
        float g7v[RR];
#pragma unroll
        for (int s = 0; s < RR; ++s) g7v[s] = G7[s * NN + n7];
        float u[RR];
#pragma unroll
        for (int r = 0; r < RR; ++r) {
            float acc = 0.f;
#pragma unroll
            for (int s = 0; s < RR; ++s)
                acc += G6[r * NR + n6 * RR + s] * g7v[s];
            u[r] = acc;
        }
        *(uint4*)(wsb + U67_OFF + n6 * 2048 + n7 * 8) = pack8bf(u);
    } else {
        // transpose G2..G5 -> Gt[n][r][s] bf16
        const int q = bid - 2 * NN;        // 0..31
        const int k = q >> 3;              // 0..3 -> G2..G5
        const int chunk = q & 7;
        const float* __restrict__ Gk =
            (k == 0) ? G2 : (k == 1) ? G3 : (k == 2) ? G4 : G5;
        const int n = chunk * 32 + (t >> 3);
        const int r = t & 7;
        const float4* src = (const float4*)(Gk + r * NR + n * RR);
        float4 x = src[0], y = src[1];
        float a[8] = {x.x, x.y, x.z, x.w, y.x, y.y, y.z, y.w};
        *(uint4*)(wsb + GT_OFF + k * 16384 + n * 64 + r * 8) = pack8bf(a);
    }
}

#define BF2F_LO(u) __uint_as_float((u) << 16)
#define BF2F_HI(u) __uint_as_float((u) & 0xFFFF0000u)

// one chain stage: v = v @ M, M = 8x8 bf16 matrix contiguous at mp
#define BSTAGE(koff, nidx)                                                  \
    do {                                                                    \
        const uint4* mp =                                                   \
            (const uint4*)(wsb + GT_OFF + (koff)*16384 + (nidx)*64);        \
        float nv0 = 0.f, nv1 = 0.f, nv2 = 0.f, nv3 = 0.f;                   \
        float nv4 = 0.f, nv5 = 0.f, nv6 = 0.f, nv7 = 0.f;                   \
        _Pragma("unroll") for (int r = 0; r < 8; ++r) {                     \
            uint4 u = mp[r];                                                \
            float vr = v[r];                                                \
            nv0 += vr * BF2F_LO(u.x); nv1 += vr * BF2F_HI(u.x);             \
            nv2 += vr * BF2F_LO(u.y); nv3 += vr * BF2F_HI(u.y);             \
            nv4 += vr * BF2F_LO(u.z); nv5 += vr * BF2F_HI(u.z);             \
            nv6 += vr * BF2F_LO(u.w); nv7 += vr * BF2F_HI(u.w);             \
        }                                                                   \
        v[0] = nv0; v[1] = nv1; v[2] = nv2; v[3] = nv3;                     \
        v[4] = nv4; v[5] = nv5; v[6] = nv6; v[7] = nv7;                     \
    } while (0)

__global__ __launch_bounds__(256) void tt_gather(
    const unsigned short* __restrict__ wsb,
    const int* __restrict__ states, const int* __restrict__ actions,
    float* __restrict__ out, int B) {
    __shared__ int ibuf[NN * 7];   // 7 KB: this block's 256 state rows

    const int t = threadIdx.x;
    const int b = blockIdx.x * 256 + t;

    // coalesced staging of states rows
    {
        const int* gsrc = states + (size_t)blockIdx.x * 256 * 7;
        const int lim = B * 7 - blockIdx.x * 256 * 7;
#pragma unroll
        for (int k = 0; k < 7; ++k) {
            int j = t + (k << 8);
            if (j < lim) ibuf[j] = gsrc[j];
        }
    }
    __syncthreads();

    const bool active = (b < B);
    const int* row = ibuf + t * 7;            // stride 7: conflict-free
    const int s0 = row[0] & 255;
    const int s1 = row[1] & 255;
    const int s2 = row[2] & 255;
    const int s3 = row[3] & 255;
    const int s4 = row[4] & 255;
    const int s5 = row[5] & 255;
    const int s6 = row[6] & 255;
    const int a7 = actions[active ? b : 0] & 255;

    float v[8];
    {
        uint4 u = *(const uint4*)(wsb + s0 * 2048 + s1 * 8);
        v[0] = BF2F_LO(u.x); v[1] = BF2F_HI(u.x);
        v[2] = BF2F_LO(u.y); v[3] = BF2F_HI(u.y);
        v[4] = BF2F_LO(u.z); v[5] = BF2F_HI(u.z);
        v[6] = BF2F_LO(u.w); v[7] = BF2F_HI(u.w);
    }

    BSTAGE(0, s2);
    BSTAGE(1, s3);
    BSTAGE(2, s4);
    BSTAGE(3, s5);

    float q;
    {
        uint4 u = *(const uint4*)(wsb + U67_OFF + s6 * 2048 + a7 * 8);
        q = v[0] * BF2F_LO(u.x) + v[1] * BF2F_HI(u.x)
          + v[2] * BF2F_LO(u.y) + v[3] * BF2F_HI(u.y)
          + v[4] * BF2F_LO(u.z) + v[5] * BF2F_HI(u.z)
          + v[6] * BF2F_LO(u.w) + v[7] * BF2F_HI(u.w);
    }
    if (active) out[b] = q;
}

extern "C" void kernel_launch(void* const* d_in, const int* in_sizes, int n_in,
                              void* d_out, int out_size, void* d_ws, size_t ws_size,
                              hipStream_t stream) {
    const float* G0 = (const float*)d_in[0];
    const float* G1 = (const float*)d_in[1];
    const float* G2 = (const float*)d_in[2];
    const float* G3 = (const float*)d_in[3];
    const float* G4 = (const float*)d_in[4];
    const float* G5 = (const float*)d_in[5];
    const float* G6 = (const float*)d_in[6];
    const float* G7 = (const float*)d_in[7];
    const int* states  = (const int*)d_in[8];
    const int* actions = (const int*)d_in[9];
    float* out = (float*)d_out;
    int B = in_sizes[9];

    unsigned short* wsb = (unsigned short*)d_ws;   // ~2.1 MB used

    hipLaunchKernelGGL(build_tables, dim3(2 * NN + 32), dim3(256), 0, stream,
                       G0, G1, G2, G3, G4, G5, G6, G7, wsb);

    hipLaunchKernelGGL(tt_gather, dim3((B + 255) / 256), dim3(256), 0, stream,
                       wsb, states, actions, out, B);
}